// Round 13
// baseline (1122.325 us; speedup 1.0000x reference)
//
#include <hip/hip_runtime.h>
#include <math.h>

#define LL   2048
#define BB   8
#define CC   32
#define CHH  256
#define HH   8
#define DD   6

typedef _Float16 h8 __attribute__((ext_vector_type(8)));
typedef _Float16 h4 __attribute__((ext_vector_type(4)));
typedef float f4 __attribute__((ext_vector_type(4)));

// ---------------------------------------------------------------- encoder
__global__ __launch_bounds__(256) void k_enc(const float* __restrict__ x,
    const float* __restrict__ W, const float* __restrict__ bias,
    float* __restrict__ X) {
  int idx = blockIdx.x * 256 + threadIdx.x;          // B*32*L = 524288
  int l = idx & (LL - 1);
  int c = (idx >> 11) & 31;
  int b = idx >> 16;
  float s = bias[c];
#pragma unroll
  for (int i = 0; i < 6; ++i)
    s = fmaf(W[c * 6 + i], x[((size_t)b * 6 + i) * LL + l], s);
  X[idx] = s;
}

// ---------------- fused QKV: pointwise conv + depthwise3/15 + gate + layout
// One block = (z, bh, 128-l tile). Stages X fp32 tile (+-8 halo, zero-fill;
// pw has no bias so pw(0)=0 == reference 'same' padding), computes pw in
// regs, packs f16 to LDS, then depthwise+gate+cvt+transpose (dwt3 logic).
// out: z=0 Qt [bh][l][32c] (scaled by C^-.5*log2e), z=1 Kt same, z=2 Vt
// [bh][32c][l].
__global__ __launch_bounds__(256) void k_qkv(const float* __restrict__ X,
    const float* __restrict__ pwq, const float* __restrict__ pwk,
    const float* __restrict__ pwv,
    const float* __restrict__ d3q, const float* __restrict__ d15q, const float* __restrict__ gq,
    const float* __restrict__ d3k, const float* __restrict__ d15k, const float* __restrict__ gk,
    const float* __restrict__ d3v, const float* __restrict__ d15v, const float* __restrict__ gv,
    _Float16* __restrict__ Qt, _Float16* __restrict__ Kt, _Float16* __restrict__ Vt) {
  // LDS: Ps [32co][304B] f16 @0; Xs [32ci][144] f32 @9728 (transpose area
  // ot aliases Xs after pw phase); Wl [32co][33] f32 @28160. Total 32384.
  __shared__ __align__(16) char lds[32384];
  char*  Ps = lds;
  float* Xs = (float*)(lds + 9728);
  float* Wl = (float*)(lds + 28160);
  const int t  = threadIdx.x;
  const int lt = blockIdx.x;                   // 0..15
  const int z  = blockIdx.y;                   // 0..2
  const int bh = blockIdx.z;                   // 0..63
  const int b = bh >> 3, h = bh & 7, l0 = lt * 128;

  // ---- stage pw weights for this head: Wl[co][ci], stride 33 (bank-spread)
  {
    const float* Wg = ((z == 0) ? pwq : (z == 1) ? pwk : pwv) + h * 1024;
    float4 w4 = ((const float4*)Wg)[t];
    int co = t >> 3, c4 = (t & 7) * 4;
    Wl[co * 33 + c4 + 0] = w4.x;  Wl[co * 33 + c4 + 1] = w4.y;
    Wl[co * 33 + c4 + 2] = w4.z;  Wl[co * 33 + c4 + 3] = w4.w;
  }
  // ---- stage X tile [32][144] (cols = l0-8 .. l0+136), zero-filled halo
  const float* Xb = X + (size_t)b * 32 * LL;
  for (int i = t; i < 1152; i += 256) {
    int row = i / 36, c4 = (i % 36) * 4;
    int gl = l0 - 8 + c4;
    float4 v = {0.f, 0.f, 0.f, 0.f};
    if (gl >= 0 && gl + 3 < LL) {
      v = *(const float4*)(Xb + (size_t)row * LL + gl);
    } else {
      float* pv = (float*)&v;
#pragma unroll
      for (int e = 0; e < 4; ++e) {
        int ge = gl + e;
        if (ge >= 0 && ge < LL) pv[e] = Xb[(size_t)row * LL + ge];
      }
    }
    *(float4*)(Xs + row * 144 + c4) = v;
  }
  __syncthreads();

  // ---- pointwise: thread (co = t&31, lg = t>>5) computes 18 l positions
  {
    int co = t & 31, lg = t >> 5;
    float acc[18];
#pragma unroll
    for (int j = 0; j < 18; ++j) acc[j] = 0.f;
    for (int ci = 0; ci < 32; ++ci) {
      float w = Wl[co * 33 + ci];
      const float2* xr = (const float2*)(Xs + ci * 144 + lg * 18);
#pragma unroll
      for (int jj = 0; jj < 9; ++jj) {
        float2 xv = xr[jj];
        acc[jj * 2 + 0] = fmaf(w, xv.x, acc[jj * 2 + 0]);
        acc[jj * 2 + 1] = fmaf(w, xv.y, acc[jj * 2 + 1]);
      }
    }
    char* pr = Ps + co * 304 + lg * 36;
#pragma unroll
    for (int jj = 0; jj < 9; ++jj) {
      unsigned u = __builtin_bit_cast(unsigned,
          __builtin_amdgcn_cvt_pkrtz(acc[jj * 2], acc[jj * 2 + 1]));
      *(unsigned*)(pr + jj * 4) = u;
    }
  }
  __syncthreads();

  // ---- depthwise conv3+conv15 + gate + cvt + layout (dwt3 phase)
  const float* w3p  = (z == 0) ? d3q  : (z == 1) ? d3k  : d3v;
  const float* w15p = (z == 0) ? d15q : (z == 1) ? d15k : d15v;
  const float* gp   = (z == 0) ? gq   : (z == 1) ? gk   : gv;
  int c = t & 31, cg = t >> 5;
  float wv[32];
  {
    const h8* wp = (const h8*)(Ps + c * 304 + cg * 32);
#pragma unroll
    for (int q4 = 0; q4 < 4; ++q4) {
      h8 v = wp[q4];
#pragma unroll
      for (int e = 0; e < 8; ++e) wv[q4 * 8 + e] = (float)v[e];
    }
  }
  float r0 = gp[0], r1 = gp[1];
  float mx = fmaxf(r0, r1);
  float e0 = __expf(r0 - mx), e1 = __expf(r1 - mx);
  float gi = 1.f / (e0 + e1);
  float g0 = e0 * gi, g1 = e1 * gi;
  float sc = (z == 0) ? 0.2550765737f : 1.0f;   // C^-0.5 * log2(e) fold
  int ch = h * 32 + c;
  float w3r[3], w15r[15];
#pragma unroll
  for (int k = 0; k < 3; ++k)  w3r[k]  = w3p[ch * 3 + k];
#pragma unroll
  for (int k = 0; k < 15; ++k) w15r[k] = w15p[ch * 15 + k];

  h8 olo, ohi;
#pragma unroll
  for (int i = 0; i < 16; ++i) {
    float a = 0.f;
#pragma unroll
    for (int k = 0; k < 3; ++k) a = fmaf(w3r[k], wv[i + 7 + k], a);
    float s15 = 0.f;
#pragma unroll
    for (int k = 0; k < 15; ++k) s15 = fmaf(w15r[k], wv[i + 1 + k], s15);
    float val = (g0 * a + g1 * s15) * sc;
    if (i < 8) olo[i] = (_Float16)val; else ohi[i - 8] = (_Float16)val;
  }

  if (z == 2) {
    _Float16* dst = Vt + ((size_t)bh * 32 + c) * LL + l0 + cg * 16;
    *(h8*)dst = olo;
    *(h8*)(dst + 8) = ohi;
  } else {
    char* ot = (char*)Xs;                       // Xs dead; 10240B transpose buf
#pragma unroll
    for (int i = 0; i < 16; ++i) {
      _Float16 v = (i < 8) ? olo[i] : ohi[i - 8];
      *(_Float16*)(ot + (cg * 16 + i) * 80 + c * 2) = v;
    }
    __syncthreads();
    _Float16* dst = ((z == 0) ? Qt : Kt) + ((size_t)bh * LL + l0) * 32;
    int l = t >> 1, hf = t & 1;
    uint4 a = *(uint4*)(ot + l * 80 + hf * 32);
    uint4 b2 = *(uint4*)(ot + l * 80 + hf * 32 + 16);
    *(uint4*)(dst + (size_t)l * 32 + hf * 16) = a;
    *(uint4*)(dst + (size_t)l * 32 + hf * 16 + 8) = b2;
  }
}

// ------------------------------------------------ MFMA flash attention (f16)
// In-block key-split: 512 thr = 8 waves; waves 0-3 keys [0,1024), waves 4-7
// keys [1024,2048), same 256 q. Single K/V LDS buffer per segment + register
// prefetch (2 barriers/tile). No-max exp2 softmax; per-q softmax denominator
// computed on the MFMA pipe via ones-row A operand (reuses pf; all C rows
// equal the 32-key column sum -> no VALU adds, no epilogue shuffles).
// Exact in-LDS merge of the two segments (fp32), normalize once, f16 out.
#define KOFF 0
#define VOFF 10240
#define POFF 19456
__global__ __launch_bounds__(512, 2) void k_attn(
    const _Float16* __restrict__ Qt, const _Float16* __restrict__ Kt,
    const _Float16* __restrict__ Vt, _Float16* __restrict__ AO) {
  __shared__ __align__(16) char lds[60416];
  const int tid  = threadIdx.x;
  const int lane = tid & 63;
  const int w    = tid >> 6;                   // 0..7
  const int seg  = w >> 2;                     // 0..1: key segment
  const int wq   = w & 3;                      // q sub-block within 256
  const int g    = lane >> 4;
  const int ln   = lane & 15;
  const int h2c  = (wq >> 1) * 2;
  const int qb   = blockIdx.x;                 // 0..7
  const int bh   = blockIdx.y;                 // 0..63
  const _Float16* Qg = Qt + ((size_t)bh * LL + qb * 256) * 32;
  const _Float16* Kg = Kt + ((size_t)bh * LL + seg * 1024) * 32;
  const _Float16* Vg = Vt + (size_t)bh * 32 * LL + seg * 1024;

  h8 qf[4];
#pragma unroll
  for (int nt = 0; nt < 4; ++nt)
    qf[nt] = *(const h8*)(Qg + (size_t)(wq * 64 + nt * 16 + ln) * 32 + g * 8);

  h8 ones;
#pragma unroll
  for (int j = 0; j < 8; ++j) ones[j] = (_Float16)1.0f;

  char* kb = lds + KOFF + seg * 5120;
  char* vb = lds + VOFF + seg * 4608;
  char* pw = lds + POFF + w * 5120;

  uint4 stg0, stg1;
  if ((wq & 1) == 0) {
    const uint4* gk = (const uint4*)Kg;
    stg0 = gk[h2c * 64 + lane];
    stg1 = gk[(h2c + 1) * 64 + lane];
    *(uint4*)(kb + (h2c * 16 + (lane >> 2)) * 80 + (lane & 3) * 16) = stg0;
    *(uint4*)(kb + ((h2c + 1) * 16 + (lane >> 2)) * 80 + (lane & 3) * 16) = stg1;
  } else {
    int c0 = h2c * 8 + (lane >> 3);
    stg0 = *(const uint4*)(Vg + (size_t)c0 * LL + (lane & 7) * 8);
    stg1 = *(const uint4*)(Vg + (size_t)(c0 + 8) * LL + (lane & 7) * 8);
    *(uint4*)(vb + c0 * 144 + (lane & 7) * 16) = stg0;
    *(uint4*)(vb + (c0 + 8) * 144 + (lane & 7) * 16) = stg1;
  }
  __syncthreads();

  f4 o[2][4];
#pragma unroll
  for (int ct = 0; ct < 2; ++ct)
#pragma unroll
    for (int nt = 0; nt < 4; ++nt) o[ct][nt] = (f4){0.f, 0.f, 0.f, 0.f};
  f4 sacc[4];
#pragma unroll
  for (int nt = 0; nt < 4; ++nt) sacc[nt] = (f4){0.f, 0.f, 0.f, 0.f};

  for (int it = 0; it < 16; ++it) {
    if (it < 15) {                             // prefetch next tile to regs
      int k0n = (it + 1) * 64;
      if ((wq & 1) == 0) {
        const uint4* gk = (const uint4*)(Kg + (size_t)k0n * 32);
        stg0 = gk[h2c * 64 + lane];
        stg1 = gk[(h2c + 1) * 64 + lane];
      } else {
        int c0 = h2c * 8 + (lane >> 3);
        stg0 = *(const uint4*)(Vg + (size_t)c0 * LL + k0n + (lane & 7) * 8);
        stg1 = *(const uint4*)(Vg + (size_t)(c0 + 8) * LL + k0n + (lane & 7) * 8);
      }
    }
#pragma unroll
    for (int chunk = 0; chunk < 2; ++chunk) {
      f4 st[2][4];
#pragma unroll
      for (int mt2 = 0; mt2 < 2; ++mt2) {
        h8 kf = *(const h8*)(kb + ((chunk * 2 + mt2) * 16 + ln) * 80 + g * 16);
#pragma unroll
        for (int nt = 0; nt < 4; ++nt) {
          f4 z = {0.f, 0.f, 0.f, 0.f};
          st[mt2][nt] = __builtin_amdgcn_mfma_f32_16x16x32_f16(kf, qf[nt], z, 0, 0, 0);
        }
      }
#pragma unroll
      for (int mt2 = 0; mt2 < 2; ++mt2)
#pragma unroll
        for (int nt = 0; nt < 4; ++nt) {
          float p0 = exp2f(st[mt2][nt][0]);
          float p1 = exp2f(st[mt2][nt][1]);
          float p2 = exp2f(st[mt2][nt][2]);
          float p3 = exp2f(st[mt2][nt][3]);
          unsigned lo = __builtin_bit_cast(unsigned, __builtin_amdgcn_cvt_pkrtz(p0, p1));
          unsigned hi = __builtin_bit_cast(unsigned, __builtin_amdgcn_cvt_pkrtz(p2, p3));
          uint2 pk; pk.x = lo; pk.y = hi;
          *(uint2*)(pw + (nt * 16 + ln) * 80 + mt2 * 32 + g * 8) = pk;
        }
      h8 vf[2];
#pragma unroll
      for (int ct = 0; ct < 2; ++ct)
        vf[ct] = *(const h8*)(vb + (ct * 16 + ln) * 144 + chunk * 64 + g * 16);
#pragma unroll
      for (int nt = 0; nt < 4; ++nt) {
        h8 pf = *(const h8*)(pw + (nt * 16 + ln) * 80 + g * 16);
        sacc[nt] = __builtin_amdgcn_mfma_f32_16x16x32_f16(ones, pf, sacc[nt], 0, 0, 0);
#pragma unroll
        for (int ct = 0; ct < 2; ++ct)
          o[ct][nt] = __builtin_amdgcn_mfma_f32_16x16x32_f16(vf[ct], pf,
                                                             o[ct][nt], 0, 0, 0);
      }
    }
    __syncthreads();
    if (it < 15) {
      if ((wq & 1) == 0) {
        *(uint4*)(kb + (h2c * 16 + (lane >> 2)) * 80 + (lane & 3) * 16) = stg0;
        *(uint4*)(kb + ((h2c + 1) * 16 + (lane >> 2)) * 80 + (lane & 3) * 16) = stg1;
      } else {
        int c0 = h2c * 8 + (lane >> 3);
        *(uint4*)(vb + c0 * 144 + (lane & 7) * 16) = stg0;
        *(uint4*)(vb + (c0 + 8) * 144 + (lane & 7) * 16) = stg1;
      }
      __syncthreads();
    }
  }

  if (seg == 1) {
    char* eo = lds + POFF + wq * 9216 + lane * 144;
#pragma unroll
    for (int nt = 0; nt < 4; ++nt)
#pragma unroll
      for (int ct = 0; ct < 2; ++ct)
        *(f4*)(eo + (nt * 2 + ct) * 16) = o[ct][nt];
    f4 sv;
    sv[0] = sacc[0][0]; sv[1] = sacc[1][0];
    sv[2] = sacc[2][0]; sv[3] = sacc[3][0];
    *(f4*)(eo + 128) = sv;
  }
  __syncthreads();
  if (seg == 0) {
    const char* po = lds + POFF + wq * 9216 + lane * 144;
    f4 s1v = *(const f4*)(po + 128);
    _Float16* out = AO + (size_t)bh * (32 * LL);
#pragma unroll
    for (int nt = 0; nt < 4; ++nt) {
      float inv = 1.f / (sacc[nt][0] + s1v[nt]);
      int qg = qb * 256 + wq * 64 + nt * 16 + ln;
#pragma unroll
      for (int ct = 0; ct < 2; ++ct) {
        f4 o1 = *(const f4*)(po + (nt * 2 + ct) * 16);
#pragma unroll
        for (int r = 0; r < 4; ++r)
          out[(size_t)(ct * 16 + g * 4 + r) * LL + qg] =
              (_Float16)((o[ct][nt][r] + o1[r]) * inv);
      }
    }
  }
}

// -------- uni GEMM [32,256] f16-in + bias + residual; L-split 16, cc-split 2
__global__ __launch_bounds__(256) void k_uni_res(const _Float16* __restrict__ AO,
    const float* __restrict__ W, const float* __restrict__ bias,
    const float* __restrict__ Xin, float* __restrict__ Y) {
  __shared__ float ps[128 * 17];
  int t    = threadIdx.x;
  int li   = t & 127;
  int cg   = t >> 7;                            // 0..1: channel half
  int bx   = blockIdx.x;                        // 256 blocks
  int lt   = bx & 15;
  int half = (bx >> 4) & 1;
  int b    = bx >> 5;
  int l    = lt * 128 + li;
  const _Float16* ap = AO + (size_t)b * CHH * LL + cg * 128 * (size_t)LL + l;
  float acc[16];
#pragma unroll
  for (int j = 0; j < 16; ++j) acc[j] = 0.f;
  for (int cc = 0; cc < 128; cc += 4) {
    float a0 = (float)ap[(size_t)(cc + 0) * LL];
    float a1 = (float)ap[(size_t)(cc + 1) * LL];
    float a2 = (float)ap[(size_t)(cc + 2) * LL];
    float a3 = (float)ap[(size_t)(cc + 3) * LL];
#pragma unroll
    for (int j = 0; j < 16; ++j) {
      const float* wr = W + (half * 16 + j) * CHH + cg * 128 + cc;
      acc[j] = fmaf(wr[0], a0, acc[j]);
      acc[j] = fmaf(wr[1], a1, acc[j]);
      acc[j] = fmaf(wr[2], a2, acc[j]);
      acc[j] = fmaf(wr[3], a3, acc[j]);
    }
  }
  if (cg) {
#pragma unroll
    for (int j = 0; j < 16; ++j) ps[li * 17 + j] = acc[j];
  }
  __syncthreads();
  if (!cg) {
#pragma unroll
    for (int j = 0; j < 16; ++j) {
      int c = half * 16 + j;
      size_t o = ((size_t)b * CC + c) * LL + l;
      Y[o] = acc[j] + ps[li * 17 + j] + bias[c] + Xin[o];
    }
  }
}

// ---------------------------------------------------------- instance norm
__global__ __launch_bounds__(256) void k_inorm(const float* __restrict__ Y,
    float* __restrict__ X, const float* __restrict__ g,
    const float* __restrict__ bt) {
  __shared__ float red[8];
  int row = blockIdx.x;
  int c = row & 31;
  const float* y = Y + (size_t)row * LL;
  float v[8];
  float s = 0.f, ss = 0.f;
#pragma unroll
  for (int i = 0; i < 8; ++i) {
    v[i] = y[threadIdx.x + 256 * i];
    s += v[i];
    ss = fmaf(v[i], v[i], ss);
  }
#pragma unroll
  for (int off = 32; off; off >>= 1) {
    s  += __shfl_down(s, off);
    ss += __shfl_down(ss, off);
  }
  int wid = threadIdx.x >> 6;
  if ((threadIdx.x & 63) == 0) { red[wid * 2] = s; red[wid * 2 + 1] = ss; }
  __syncthreads();
  if (threadIdx.x == 0) {
    red[0] = red[0] + red[2] + red[4] + red[6];
    red[1] = red[1] + red[3] + red[5] + red[7];
  }
  __syncthreads();
  float mean = red[0] * (1.f / LL);
  float var  = red[1] * (1.f / LL) - mean * mean;
  float rs = rsqrtf(var + 1e-5f) * g[c];
  float bb = bt[c];
#pragma unroll
  for (int i = 0; i < 8; ++i)
    X[(size_t)row * LL + threadIdx.x + 256 * i] = (v[i] - mean) * rs + bb;
}

// -------- fused FFN: relu(W1 x + b1) -> W2 + b2 + residual; 64-l tiles,
// 4 o-groups in-block combined via LDS. grid 256.
__global__ __launch_bounds__(256) void k_ffn(const float* __restrict__ X,
    const float* __restrict__ W1, const float* __restrict__ b1,
    const float* __restrict__ W2, const float* __restrict__ b2,
    float* __restrict__ Y) {
  __shared__ float ps[3][64 * 33];
  int bx = blockIdx.x;                          // 8b * 32lt
  int b = bx >> 5;
  int l0 = (bx & 31) * 64;
  int t = threadIdx.x;
  int li = t & 63;
  int og = t >> 6;                              // 0..3
  int l = l0 + li;
  const float* Xp = X + (size_t)b * CC * LL + l;
  float xv[32];
#pragma unroll
  for (int c = 0; c < 32; ++c) xv[c] = Xp[(size_t)c * LL];
  float acc[32];
#pragma unroll
  for (int c = 0; c < 32; ++c) acc[c] = 0.f;
  for (int o = og * 32; o < og * 32 + 32; ++o) {
    float hs = b1[o];
#pragma unroll
    for (int c = 0; c < 32; ++c) hs = fmaf(W1[o * 32 + c], xv[c], hs);
    hs = fmaxf(hs, 0.f);
#pragma unroll
    for (int c = 0; c < 32; ++c) acc[c] = fmaf(W2[c * 128 + o], hs, acc[c]);
  }
  if (og) {
#pragma unroll
    for (int c = 0; c < 32; ++c) ps[og - 1][li * 33 + c] = acc[c];
  }
  __syncthreads();
  if (!og) {
    float* Yp = Y + (size_t)b * CC * LL + l;
#pragma unroll
    for (int c = 0; c < 32; ++c)
      Yp[(size_t)c * LL] = acc[c] + ps[0][li * 33 + c] + ps[1][li * 33 + c] +
                           ps[2][li * 33 + c] + b2[c] + xv[c];
  }
}

// ------------------------------------------------------------- classifier
__global__ __launch_bounds__(256) void k_cls(const float* __restrict__ X,
    const float* __restrict__ W, const float* __restrict__ bias,
    float* __restrict__ out) {
  int idx = blockIdx.x * 256 + threadIdx.x;
  int l = idx & (LL - 1);
  int b = idx >> 11;
  float s = bias[0];
#pragma unroll
  for (int c = 0; c < CC; ++c)
    s = fmaf(W[c], X[((size_t)b * CC + c) * LL + l], s);
  out[idx] = 1.f / (1.f + __expf(-s));
}

// ------------------------------------------------------------------ launch
extern "C" void kernel_launch(void* const* d_in, const int* in_sizes, int n_in,
                              void* d_out, int out_size, void* d_ws,
                              size_t ws_size, hipStream_t stream) {
  const float* x      = (const float*)d_in[0];
  const float* enc_W  = (const float*)d_in[1];
  const float* enc_b  = (const float*)d_in[2];
  const float* pw_q   = (const float*)d_in[3];
  const float* dw3_q  = (const float*)d_in[4];
  const float* dw15_q = (const float*)d_in[5];
  const float* gate_q = (const float*)d_in[6];
  const float* pw_k   = (const float*)d_in[7];
  const float* dw3_k  = (const float*)d_in[8];
  const float* dw15_k = (const float*)d_in[9];
  const float* gate_k = (const float*)d_in[10];
  const float* pw_v   = (const float*)d_in[11];
  const float* dw3_v  = (const float*)d_in[12];
  const float* dw15_v = (const float*)d_in[13];
  const float* gate_v = (const float*)d_in[14];
  const float* uni_W  = (const float*)d_in[15];
  const float* uni_b  = (const float*)d_in[16];
  const float* n1_g   = (const float*)d_in[17];
  const float* n1_b   = (const float*)d_in[18];
  const float* n2_g   = (const float*)d_in[19];
  const float* n2_b   = (const float*)d_in[20];
  const float* ffn_W1 = (const float*)d_in[21];
  const float* ffn_b1 = (const float*)d_in[22];
  const float* ffn_W2 = (const float*)d_in[23];
  const float* ffn_b2 = (const float*)d_in[24];
  const float* cls_W  = (const float*)d_in[25];
  const float* cls_b  = (const float*)d_in[26];

  float* ws = (float*)d_ws;
  float* X   = ws;                             // [B,32,L] fp32
  float* Y   = ws + 524288;                    // [B,32,L] fp32
  _Float16* AO = (_Float16*)(ws + 1048576);    // [B,256,L] f16 attn out
  _Float16* Qt = (_Float16*)(ws + 9437184);    // [64bh][L][32c] f16
  _Float16* Kt = (_Float16*)(ws + 11534336);   // [64bh][L][32c] f16
  _Float16* Vt = (_Float16*)(ws + 13631488);   // [64bh][32c][L] f16

  k_enc<<<2048, 256, 0, stream>>>(x, enc_W, enc_b, X);

  for (int d = 0; d < DD; ++d) {
    k_qkv<<<dim3(16, 3, 64), 256, 0, stream>>>(X,
        pw_q + d * CHH * CC, pw_k + d * CHH * CC, pw_v + d * CHH * CC,
        dw3_q + d * CHH * 3, dw15_q + d * CHH * 15, gate_q + d * 2,
        dw3_k + d * CHH * 3, dw15_k + d * CHH * 15, gate_k + d * 2,
        dw3_v + d * CHH * 3, dw15_v + d * CHH * 15, gate_v + d * 2,
        Qt, Kt, Vt);
    k_attn<<<dim3(8, 64), 512, 0, stream>>>(Qt, Kt, Vt, AO);
    k_uni_res<<<256, 256, 0, stream>>>(AO, uni_W + d * CC * CHH,
                                       uni_b + d * CC, X, Y);
    k_inorm<<<256, 256, 0, stream>>>(Y, X, n1_g + d * CC, n1_b + d * CC);
    k_ffn<<<256, 256, 0, stream>>>(X, ffn_W1 + d * 128 * CC, ffn_b1 + d * 128,
                                   ffn_W2 + d * CC * 128, ffn_b2 + d * CC, Y);
    k_inorm<<<256, 256, 0, stream>>>(Y, X, n2_g + d * CC, n2_b + d * CC);
  }

  k_cls<<<64, 256, 0, stream>>>(X, cls_W, cls_b, (float*)d_out);
}